// Round 3
// baseline (734.891 us; speedup 1.0000x reference)
//
#include <hip/hip_runtime.h>

#define N_GRAPHS 64

// ---------------------------------------------------------------------------
// CSR build stage 1: in-degree count (self-loop handled analytically later)
__global__ void k_deg(const int* __restrict__ col, int* __restrict__ deg, int E) {
    int e = blockIdx.x * blockDim.x + threadIdx.x;
    if (e < E) atomicAdd(&deg[col[e]], 1);
}

// dinv[i] = rsqrt(deg[i]+1);  xs[i][k] = x[i][k] * dinv[i]
__global__ void k_prep(const int* __restrict__ deg, const float* __restrict__ x,
                       float* __restrict__ dinv, float* __restrict__ xs, int n) {
    int i = blockIdx.x * blockDim.x + threadIdx.x;
    if (i >= n) return;
    float d = rsqrtf((float)(deg[i] + 1));
    dinv[i] = d;
#pragma unroll
    for (int k = 0; k < 7; k++) xs[(size_t)i * 7 + k] = x[(size_t)i * 7 + k] * d;
}

// ---------------------------------------------------------------------------
// Exclusive scan of deg -> off.  1024 elements per 256-thread block.
__global__ __launch_bounds__(256) void k_scan_partial(
        const int* __restrict__ deg, int* __restrict__ off,
        int* __restrict__ bsum, int n) {
    __shared__ int lds[256];
    int t = threadIdx.x;
    int base = blockIdx.x * 1024 + t * 4;
    int v[4], s = 0;
#pragma unroll
    for (int q = 0; q < 4; q++) {
        v[q] = (base + q < n) ? deg[base + q] : 0;
        s += v[q];
    }
    lds[t] = s;
    __syncthreads();
    for (int d = 1; d < 256; d <<= 1) {
        int tmp = (t >= d) ? lds[t - d] : 0;
        __syncthreads();
        lds[t] += tmp;
        __syncthreads();
    }
    int run = lds[t] - s;
#pragma unroll
    for (int q = 0; q < 4; q++) {
        if (base + q < n) off[base + q] = run;
        run += v[q];
    }
    if (t == 255) bsum[blockIdx.x] = lds[255];
}

__global__ void k_scan_blocks(const int* __restrict__ bsum,
                              int* __restrict__ bexcl, int nb) {
    __shared__ int lds[128];
    int t = threadIdx.x;
    int v = (t < nb) ? bsum[t] : 0;
    lds[t] = v;
    __syncthreads();
    for (int d = 1; d < 128; d <<= 1) {
        int tmp = (t >= d) ? lds[t - d] : 0;
        __syncthreads();
        lds[t] += tmp;
        __syncthreads();
    }
    if (t < nb) bexcl[t] = lds[t] - v;
}

__global__ void k_scan_add(int* __restrict__ off, const int* __restrict__ bexcl,
                           int n, int E) {
    int i = blockIdx.x * blockDim.x + threadIdx.x;
    if (i < n) off[i] += bexcl[i >> 10];
    if (i == 0) off[n] = E;
}

// CSR build stage 2: scatter edge sources into per-target buckets.
// cursor starts as a copy of off, so slot = atomicAdd(&cursor[c],1) directly.
__global__ void k_scatter(const int* __restrict__ row, const int* __restrict__ colv,
                          int* __restrict__ cursor, int* __restrict__ srow, int E) {
    int e = blockIdx.x * blockDim.x + threadIdx.x;
    if (e >= E) return;
    int r = row[e], c = colv[e];
    int p = atomicAdd(&cursor[c], 1);
    srow[p] = r;
}

// ---------------------------------------------------------------------------
// Layer-1 aggregation (gather): one wave per node, 7 features.
// lane = es*8 + f :  f in [0,8) (7 valid), es in [0,8) -> 8 edges/iter.
// aggx[c] = dinv[c] * ( sum_edges xs[r] + xs[c] )
__global__ __launch_bounds__(256) void k_agg1(
        const float* __restrict__ xs, const float* __restrict__ dinv,
        const int* __restrict__ off, const int* __restrict__ srow,
        float* __restrict__ aggx, int n) {
    int wid = (blockIdx.x * blockDim.x + threadIdx.x) >> 6;
    if (wid >= n) return;
    int lane = threadIdx.x & 63;
    int f = lane & 7, es = lane >> 3;
    int c = wid;
    int o0 = off[c], o1 = off[c + 1];
    float acc = 0.f;
    if (es == 0 && f < 7) acc = xs[(size_t)c * 7 + f];          // self loop
    for (int j = o0 + es; j < o1; j += 8) {
        int r = srow[j];
        if (f < 7) acc += xs[(size_t)r * 7 + f];
    }
    acc += __shfl_xor(acc, 8);
    acc += __shfl_xor(acc, 16);
    acc += __shfl_xor(acc, 32);
    if (es == 0 && f < 7) aggx[(size_t)c * 7 + f] = acc * dinv[c];
}

// Per node: h1 = relu(aggx @ W1 + b1)  [64];  hs = (h1 @ W2) * dinv  [32]
__global__ __launch_bounds__(256) void k_mlp1(
        const float* __restrict__ aggx, const float* __restrict__ dinv,
        const float* __restrict__ W1, const float* __restrict__ b1,
        const float* __restrict__ W2,
        float* __restrict__ hs, int n) {
    __shared__ float sW1[7 * 64];
    __shared__ float sb1[64];
    __shared__ float sW2[64 * 32];
    for (int t = threadIdx.x; t < 7 * 64; t += blockDim.x) sW1[t] = W1[t];
    for (int t = threadIdx.x; t < 64; t += blockDim.x) sb1[t] = b1[t];
    for (int t = threadIdx.x; t < 64 * 32; t += blockDim.x) sW2[t] = W2[t];
    __syncthreads();

    int i = blockIdx.x * blockDim.x + threadIdx.x;
    if (i >= n) return;

    float a[7];
#pragma unroll
    for (int k = 0; k < 7; k++) a[k] = aggx[(size_t)i * 7 + k];

    float acc[32];
#pragma unroll
    for (int m = 0; m < 32; m++) acc[m] = 0.f;

    for (int j = 0; j < 64; j++) {
        float v = sb1[j];
#pragma unroll
        for (int k = 0; k < 7; k++) v += a[k] * sW1[k * 64 + j];
        v = fmaxf(v, 0.f);  // relu(conv1)
#pragma unroll
        for (int m = 0; m < 32; m++) acc[m] += v * sW2[j * 32 + m];
    }
    float d = dinv[i];
#pragma unroll
    for (int m = 0; m < 32; m++) hs[(size_t)i * 32 + m] = acc[m] * d;
}

// Layer-2 aggregation (gather): one wave per node, 32 features.
// lane = es*32 + f : f in [0,32), es in [0,2) -> 2 edges/iter.
// agg2[c] = dinv[c] * ( sum_edges hs[r] + hs[c] )
__global__ __launch_bounds__(256) void k_agg2(
        const float* __restrict__ hs, const float* __restrict__ dinv,
        const int* __restrict__ off, const int* __restrict__ srow,
        float* __restrict__ agg2, int n) {
    int wid = (blockIdx.x * blockDim.x + threadIdx.x) >> 6;
    if (wid >= n) return;
    int lane = threadIdx.x & 63;
    int f = lane & 31, es = lane >> 5;
    int c = wid;
    int o0 = off[c], o1 = off[c + 1];
    float acc = (es == 0) ? hs[(size_t)c * 32 + f] : 0.f;       // self loop
    for (int j = o0 + es; j < o1; j += 2) {
        acc += hs[(size_t)srow[j] * 32 + f];
    }
    acc += __shfl_xor(acc, 32);
    if (es == 0) agg2[(size_t)c * 32 + f] = acc * dinv[c];
}

// Per node: h2 = relu(agg2 + b2); wave-reduce per graph (batch sorted), one
// atomic set per wave into psum/pcnt.
__global__ __launch_bounds__(256) void k_pool(
        const float* __restrict__ agg2, const float* __restrict__ b2,
        const int* __restrict__ batch,
        float* __restrict__ psum, int* __restrict__ pcnt, int n) {
    int i = blockIdx.x * blockDim.x + threadIdx.x;
    bool valid = (i < n);
    int isafe = valid ? i : (n - 1);
    int g = batch[isafe];

    float v[32];
#pragma unroll
    for (int m = 0; m < 32; m++) {
        float t = agg2[(size_t)isafe * 32 + m] + b2[m];
        v[m] = valid ? fmaxf(t, 0.f) : 0.f;
    }

    int g0 = __shfl(g, 0);
    if (__all(g == g0)) {
#pragma unroll
        for (int step = 1; step < 64; step <<= 1) {
#pragma unroll
            for (int m = 0; m < 32; m++) v[m] += __shfl_xor(v[m], step);
        }
        unsigned long long mask = __ballot(valid);
        int lane = threadIdx.x & 63;
        if (lane == 0) {
#pragma unroll
            for (int m = 0; m < 32; m++) atomicAdd(&psum[g0 * 32 + m], v[m]);
            atomicAdd(&pcnt[g0], (int)__popcll(mask));
        }
    } else {
        if (valid) {
#pragma unroll
            for (int m = 0; m < 32; m++) atomicAdd(&psum[g * 32 + m], v[m]);
            atomicAdd(&pcnt[g], 1);
        }
    }
}

// out[g][o] = (sum_m psum[g][m] * Wl[m][o]) / max(cnt,1) + bl[o]
__global__ void k_out(const float* __restrict__ psum, const int* __restrict__ pcnt,
                      const float* __restrict__ Wl, const float* __restrict__ bl,
                      float* __restrict__ out) {
    int t = blockIdx.x * blockDim.x + threadIdx.x;
    if (t >= N_GRAPHS * 5) return;
    int g = t / 5, o = t % 5;
    float c = (float)max(pcnt[g], 1);
    float acc = 0.f;
#pragma unroll
    for (int m = 0; m < 32; m++) acc += psum[g * 32 + m] * Wl[m * 5 + o];
    out[t] = acc / c + bl[o];
}

extern "C" void kernel_launch(void* const* d_in, const int* in_sizes, int n_in,
                              void* d_out, int out_size, void* d_ws, size_t ws_size,
                              hipStream_t stream) {
    const float* x     = (const float*)d_in[0];
    const int*   ei    = (const int*)d_in[1];
    const int*   batch = (const int*)d_in[2];
    const float* W1    = (const float*)d_in[3];
    const float* b1    = (const float*)d_in[4];
    const float* W2    = (const float*)d_in[5];
    const float* b2    = (const float*)d_in[6];
    const float* Wl    = (const float*)d_in[7];
    const float* bl    = (const float*)d_in[8];
    float* out = (float*)d_out;

    const int n = in_sizes[0] / 7;        // 100000
    const int E = in_sizes[1] / 2;        // 3200000
    const int* row = ei;                  // edge_index[0]
    const int* col = ei + E;              // edge_index[1]

    // workspace carve-up (256B aligned)
    char* p = (char*)d_ws;
    auto alloc = [&](size_t bytes) -> char* {
        char* r = p;
        p += (bytes + 255) & ~(size_t)255;
        return r;
    };
    int*   deg    = (int*)  alloc((size_t)n * 4);
    float* dinv   = (float*)alloc((size_t)n * 4);
    int*   off    = (int*)  alloc((size_t)(n + 1) * 4);
    int*   cursor = (int*)  alloc((size_t)n * 4);
    int*   bsum   = (int*)  alloc(128 * 4);
    int*   bexcl  = (int*)  alloc(128 * 4);
    int*   srow   = (int*)  alloc((size_t)E * 4);
    float* xs     = (float*)alloc((size_t)n * 7 * 4);
    float* aggx   = (float*)alloc((size_t)n * 7 * 4);
    float* hs     = (float*)alloc((size_t)n * 32 * 4);
    float* agg2   = (float*)alloc((size_t)n * 32 * 4);
    float* psum   = (float*)alloc((size_t)N_GRAPHS * 32 * 4);
    int*   pcnt   = (int*)  alloc((size_t)N_GRAPHS * 4);

    hipMemsetAsync(deg, 0, (size_t)n * 4, stream);
    hipMemsetAsync(psum, 0, (size_t)N_GRAPHS * 32 * 4, stream);
    hipMemsetAsync(pcnt, 0, (size_t)N_GRAPHS * 4, stream);

    const int BT = 256;
    int nb_n = (n + BT - 1) / BT;
    int nb_e = (E + BT - 1) / BT;
    int nb_scan = (n + 1023) / 1024;              // 98
    int nb_wave = (n * 64 + BT - 1) / BT;         // one wave per node

    k_deg         <<<nb_e, BT, 0, stream>>>(col, deg, E);
    k_prep        <<<nb_n, BT, 0, stream>>>(deg, x, dinv, xs, n);
    k_scan_partial<<<nb_scan, BT, 0, stream>>>(deg, off, bsum, n);
    k_scan_blocks <<<1, 128, 0, stream>>>(bsum, bexcl, nb_scan);
    k_scan_add    <<<nb_n, BT, 0, stream>>>(off, bexcl, n, E);
    hipMemcpyAsync(cursor, off, (size_t)n * 4, hipMemcpyDeviceToDevice, stream);
    k_scatter     <<<nb_e, BT, 0, stream>>>(row, col, cursor, srow, E);
    k_agg1        <<<nb_wave, BT, 0, stream>>>(xs, dinv, off, srow, aggx, n);
    k_mlp1        <<<nb_n, BT, 0, stream>>>(aggx, dinv, W1, b1, W2, hs, n);
    k_agg2        <<<nb_wave, BT, 0, stream>>>(hs, dinv, off, srow, agg2, n);
    k_pool        <<<nb_n, BT, 0, stream>>>(agg2, b2, batch, psum, pcnt, n);
    k_out         <<<1, 320, 0, stream>>>(psum, pcnt, Wl, bl, out);
}

// Round 4
// 409.205 us; speedup vs baseline: 1.7959x; 1.7959x over previous
//
#include <hip/hip_runtime.h>

#define N_GRAPHS 64
#define EPB 8192          // edges per block in binning kernels
#define MAXBK 1024        // max node-buckets supported (n <= 256K)

// ---------------------------------------------------------------------------
// Binning stage 1: per-(bucket,block) edge counts via LDS histogram.
// bucket = col >> 8 (256 nodes per bucket). No global atomics.
__global__ __launch_bounds__(256) void k_count(
        const int* __restrict__ col, int* __restrict__ cnt,
        int E, int NBLK, int NBK) {
    __shared__ int h[MAXBK];
    for (int t = threadIdx.x; t < NBK; t += 256) h[t] = 0;
    __syncthreads();
    int s = blockIdx.x * EPB, e = min(E, s + EPB);
    for (int j = s + threadIdx.x; j < e; j += 256)
        atomicAdd(&h[col[j] >> 8], 1);
    __syncthreads();
    // bucket-major layout so each bucket's segments are contiguous after scan
    for (int b = threadIdx.x; b < NBK; b += 256)
        cnt[(size_t)b * NBLK + blockIdx.x] = h[b];
}

// ---------------------------------------------------------------------------
// Generic hierarchical exclusive scan (1024 elems / 256-thread block)
__global__ __launch_bounds__(256) void k_scan_partial(
        const int* __restrict__ in, int* __restrict__ outv,
        int* __restrict__ bsum, int n) {
    __shared__ int lds[256];
    int t = threadIdx.x;
    int base = blockIdx.x * 1024 + t * 4;
    int v[4], s = 0;
#pragma unroll
    for (int q = 0; q < 4; q++) {
        v[q] = (base + q < n) ? in[base + q] : 0;
        s += v[q];
    }
    lds[t] = s;
    __syncthreads();
    for (int d = 1; d < 256; d <<= 1) {
        int tmp = (t >= d) ? lds[t - d] : 0;
        __syncthreads();
        lds[t] += tmp;
        __syncthreads();
    }
    int run = lds[t] - s;
#pragma unroll
    for (int q = 0; q < 4; q++) {
        if (base + q < n) outv[base + q] = run;
        run += v[q];
    }
    if (t == 255) bsum[blockIdx.x] = lds[255];
}

// single block scans <=256 block sums -> exclusive block offsets
__global__ __launch_bounds__(256) void k_scan_blocks(
        const int* __restrict__ bsum, int* __restrict__ bexcl, int nb) {
    __shared__ int lds[256];
    int t = threadIdx.x;
    int v = (t < nb) ? bsum[t] : 0;
    lds[t] = v;
    __syncthreads();
    for (int d = 1; d < 256; d <<= 1) {
        int tmp = (t >= d) ? lds[t - d] : 0;
        __syncthreads();
        lds[t] += tmp;
        __syncthreads();
    }
    if (t < nb) bexcl[t] = lds[t] - v;
}

__global__ void k_scan_add(int* __restrict__ outv, const int* __restrict__ bexcl,
                           int n, int E) {
    int i = blockIdx.x * blockDim.x + threadIdx.x;
    if (i < n) outv[i] += bexcl[i >> 10];
    if (i == 0) outv[n] = E;
}

// ---------------------------------------------------------------------------
// Binning stage 2: scatter packed records into per-(bucket,block) segments.
// Slots claimed from LDS cursors (no global atomics); each block owns its
// disjoint output ranges -> write lines have a single owner.
__global__ __launch_bounds__(256) void k_binscatter(
        const int* __restrict__ row, const int* __restrict__ col,
        const int* __restrict__ baseA, unsigned int* __restrict__ ebuf,
        int E, int NBLK, int NBK) {
    __shared__ int cur[MAXBK];
    for (int b = threadIdx.x; b < NBK; b += 256)
        cur[b] = baseA[(size_t)b * NBLK + blockIdx.x];
    __syncthreads();
    int s = blockIdx.x * EPB, e = min(E, s + EPB);
    for (int j = s + threadIdx.x; j < e; j += 256) {
        int c = col[j], r = row[j];
        int p = atomicAdd(&cur[c >> 8], 1);
        ebuf[p] = ((unsigned)r << 8) | (unsigned)(c & 255);   // r<2^17, local c 8b
    }
}

// Per-bucket in-degree histogram -> deg  (replaces global-atomic k_deg)
__global__ __launch_bounds__(256) void k_bhist(
        const unsigned int* __restrict__ ebuf, const int* __restrict__ baseA,
        int* __restrict__ deg, int n, int NBLK) {
    __shared__ int h[256];
    h[threadIdx.x] = 0;
    __syncthreads();
    int b = blockIdx.x;
    int s = baseA[(size_t)b * NBLK];
    int e = baseA[(size_t)(b + 1) * NBLK];
    for (int j = s + threadIdx.x; j < e; j += 256)
        atomicAdd(&h[ebuf[j] & 255], 1);
    __syncthreads();
    int node = b * 256 + threadIdx.x;
    if (node < n) deg[node] = h[threadIdx.x];
}

// Per-bucket CSR scatter: LDS cursors seeded from off; writes confined to the
// bucket's ~32KB srow window (single block -> L2-merged, written back once).
__global__ __launch_bounds__(256) void k_bscatter(
        const unsigned int* __restrict__ ebuf, const int* __restrict__ baseA,
        const int* __restrict__ off, int* __restrict__ srow,
        int n, int NBLK) {
    __shared__ int cur[256];
    int b = blockIdx.x;
    int node = b * 256 + threadIdx.x;
    cur[threadIdx.x] = (node < n) ? off[node] : 0;
    __syncthreads();
    int s = baseA[(size_t)b * NBLK];
    int e = baseA[(size_t)(b + 1) * NBLK];
    for (int j = s + threadIdx.x; j < e; j += 256) {
        unsigned rec = ebuf[j];
        int p = atomicAdd(&cur[rec & 255], 1);
        srow[p] = (int)(rec >> 8);
    }
}

// ---------------------------------------------------------------------------
// dinv[i] = rsqrt(deg[i]+1);  xs[i][k] = x[i][k] * dinv[i]
__global__ void k_prep(const int* __restrict__ deg, const float* __restrict__ x,
                       float* __restrict__ dinv, float* __restrict__ xs, int n) {
    int i = blockIdx.x * blockDim.x + threadIdx.x;
    if (i >= n) return;
    float d = rsqrtf((float)(deg[i] + 1));
    dinv[i] = d;
#pragma unroll
    for (int k = 0; k < 7; k++) xs[(size_t)i * 7 + k] = x[(size_t)i * 7 + k] * d;
}

// Layer-1 aggregation (gather): one wave per node, 7 features.
__global__ __launch_bounds__(256) void k_agg1(
        const float* __restrict__ xs, const float* __restrict__ dinv,
        const int* __restrict__ off, const int* __restrict__ srow,
        float* __restrict__ aggx, int n) {
    int wid = (blockIdx.x * blockDim.x + threadIdx.x) >> 6;
    if (wid >= n) return;
    int lane = threadIdx.x & 63;
    int f = lane & 7, es = lane >> 3;
    int c = wid;
    int o0 = off[c], o1 = off[c + 1];
    float acc = 0.f;
    if (es == 0 && f < 7) acc = xs[(size_t)c * 7 + f];          // self loop
    for (int j = o0 + es; j < o1; j += 8) {
        int r = srow[j];
        if (f < 7) acc += xs[(size_t)r * 7 + f];
    }
    acc += __shfl_xor(acc, 8);
    acc += __shfl_xor(acc, 16);
    acc += __shfl_xor(acc, 32);
    if (es == 0 && f < 7) aggx[(size_t)c * 7 + f] = acc * dinv[c];
}

// Per node: h1 = relu(aggx @ W1 + b1)  [64];  hs = (h1 @ W2) * dinv  [32]
__global__ __launch_bounds__(256) void k_mlp1(
        const float* __restrict__ aggx, const float* __restrict__ dinv,
        const float* __restrict__ W1, const float* __restrict__ b1,
        const float* __restrict__ W2,
        float* __restrict__ hs, int n) {
    __shared__ float sW1[7 * 64];
    __shared__ float sb1[64];
    __shared__ float sW2[64 * 32];
    for (int t = threadIdx.x; t < 7 * 64; t += blockDim.x) sW1[t] = W1[t];
    for (int t = threadIdx.x; t < 64; t += blockDim.x) sb1[t] = b1[t];
    for (int t = threadIdx.x; t < 64 * 32; t += blockDim.x) sW2[t] = W2[t];
    __syncthreads();

    int i = blockIdx.x * blockDim.x + threadIdx.x;
    if (i >= n) return;

    float a[7];
#pragma unroll
    for (int k = 0; k < 7; k++) a[k] = aggx[(size_t)i * 7 + k];

    float acc[32];
#pragma unroll
    for (int m = 0; m < 32; m++) acc[m] = 0.f;

    for (int j = 0; j < 64; j++) {
        float v = sb1[j];
#pragma unroll
        for (int k = 0; k < 7; k++) v += a[k] * sW1[k * 64 + j];
        v = fmaxf(v, 0.f);  // relu(conv1)
#pragma unroll
        for (int m = 0; m < 32; m++) acc[m] += v * sW2[j * 32 + m];
    }
    float d = dinv[i];
#pragma unroll
    for (int m = 0; m < 32; m++) hs[(size_t)i * 32 + m] = acc[m] * d;
}

// Layer-2 aggregation (gather): one wave per node, 32 features.
__global__ __launch_bounds__(256) void k_agg2(
        const float* __restrict__ hs, const float* __restrict__ dinv,
        const int* __restrict__ off, const int* __restrict__ srow,
        float* __restrict__ agg2, int n) {
    int wid = (blockIdx.x * blockDim.x + threadIdx.x) >> 6;
    if (wid >= n) return;
    int lane = threadIdx.x & 63;
    int f = lane & 31, es = lane >> 5;
    int c = wid;
    int o0 = off[c], o1 = off[c + 1];
    float acc = (es == 0) ? hs[(size_t)c * 32 + f] : 0.f;       // self loop
    for (int j = o0 + es; j < o1; j += 2) {
        acc += hs[(size_t)srow[j] * 32 + f];
    }
    acc += __shfl_xor(acc, 32);
    if (es == 0) agg2[(size_t)c * 32 + f] = acc * dinv[c];
}

// Per node: h2 = relu(agg2 + b2); wave-reduce per graph (batch sorted)
__global__ __launch_bounds__(256) void k_pool(
        const float* __restrict__ agg2, const float* __restrict__ b2,
        const int* __restrict__ batch,
        float* __restrict__ psum, int* __restrict__ pcnt, int n) {
    int i = blockIdx.x * blockDim.x + threadIdx.x;
    bool valid = (i < n);
    int isafe = valid ? i : (n - 1);
    int g = batch[isafe];

    float v[32];
#pragma unroll
    for (int m = 0; m < 32; m++) {
        float t = agg2[(size_t)isafe * 32 + m] + b2[m];
        v[m] = valid ? fmaxf(t, 0.f) : 0.f;
    }

    int g0 = __shfl(g, 0);
    if (__all(g == g0)) {
#pragma unroll
        for (int step = 1; step < 64; step <<= 1) {
#pragma unroll
            for (int m = 0; m < 32; m++) v[m] += __shfl_xor(v[m], step);
        }
        unsigned long long mask = __ballot(valid);
        int lane = threadIdx.x & 63;
        if (lane == 0) {
#pragma unroll
            for (int m = 0; m < 32; m++) atomicAdd(&psum[g0 * 32 + m], v[m]);
            atomicAdd(&pcnt[g0], (int)__popcll(mask));
        }
    } else {
        if (valid) {
#pragma unroll
            for (int m = 0; m < 32; m++) atomicAdd(&psum[g * 32 + m], v[m]);
            atomicAdd(&pcnt[g], 1);
        }
    }
}

// out[g][o] = (sum_m psum[g][m] * Wl[m][o]) / max(cnt,1) + bl[o]
__global__ void k_out(const float* __restrict__ psum, const int* __restrict__ pcnt,
                      const float* __restrict__ Wl, const float* __restrict__ bl,
                      float* __restrict__ out) {
    int t = blockIdx.x * blockDim.x + threadIdx.x;
    if (t >= N_GRAPHS * 5) return;
    int g = t / 5, o = t % 5;
    float c = (float)max(pcnt[g], 1);
    float acc = 0.f;
#pragma unroll
    for (int m = 0; m < 32; m++) acc += psum[g * 32 + m] * Wl[m * 5 + o];
    out[t] = acc / c + bl[o];
}

extern "C" void kernel_launch(void* const* d_in, const int* in_sizes, int n_in,
                              void* d_out, int out_size, void* d_ws, size_t ws_size,
                              hipStream_t stream) {
    const float* x     = (const float*)d_in[0];
    const int*   ei    = (const int*)d_in[1];
    const int*   batch = (const int*)d_in[2];
    const float* W1    = (const float*)d_in[3];
    const float* b1    = (const float*)d_in[4];
    const float* W2    = (const float*)d_in[5];
    const float* b2    = (const float*)d_in[6];
    const float* Wl    = (const float*)d_in[7];
    const float* bl    = (const float*)d_in[8];
    float* out = (float*)d_out;

    const int n = in_sizes[0] / 7;        // 100000
    const int E = in_sizes[1] / 2;        // 3200000
    const int* row = ei;                  // edge_index[0]
    const int* col = ei + E;              // edge_index[1]

    const int NBK  = (n + 255) >> 8;              // 391 node-buckets
    const int NBLK = (E + EPB - 1) / EPB;         // 391 edge-chunks
    const int NT   = NBK * NBLK;                  // 152881 segments

    // workspace carve-up (256B aligned)
    char* p = (char*)d_ws;
    auto alloc = [&](size_t bytes) -> char* {
        char* r = p;
        p += (bytes + 255) & ~(size_t)255;
        return r;
    };
    int*   deg    = (int*)  alloc((size_t)n * 4);
    float* dinv   = (float*)alloc((size_t)n * 4);
    int*   off    = (int*)  alloc((size_t)(n + 1) * 4);
    int*   cnt    = (int*)  alloc((size_t)NT * 4);
    int*   baseA  = (int*)  alloc((size_t)(NT + 1) * 4);
    unsigned int* ebuf = (unsigned int*)alloc((size_t)E * 4);
    int*   srow   = (int*)  alloc((size_t)E * 4);
    int*   bsum   = (int*)  alloc(256 * 4);
    int*   bexcl  = (int*)  alloc(256 * 4);
    int*   bsum2  = (int*)  alloc(256 * 4);
    int*   bexcl2 = (int*)  alloc(256 * 4);
    float* xs     = (float*)alloc((size_t)n * 7 * 4);
    float* aggx   = (float*)alloc((size_t)n * 7 * 4);
    float* hs     = (float*)alloc((size_t)n * 32 * 4);
    float* agg2   = (float*)alloc((size_t)n * 32 * 4);
    float* psum   = (float*)alloc((size_t)N_GRAPHS * 32 * 4);
    int*   pcnt   = (int*)  alloc((size_t)N_GRAPHS * 4);

    hipMemsetAsync(psum, 0, (size_t)N_GRAPHS * 32 * 4, stream);
    hipMemsetAsync(pcnt, 0, (size_t)N_GRAPHS * 4, stream);

    const int BT = 256;
    int nb_n    = (n + BT - 1) / BT;
    int nb_scanN = (n + 1023) / 1024;             // 98
    int nb_scanT = (NT + 1023) / 1024;            // 150
    int nb_wave = (n * 64 + BT - 1) / BT;         // one wave per node

    // CSR build (two-level binning, no global atomics)
    k_count      <<<NBLK, BT, 0, stream>>>(col, cnt, E, NBLK, NBK);
    k_scan_partial<<<nb_scanT, BT, 0, stream>>>(cnt, baseA, bsum2, NT);
    k_scan_blocks<<<1, BT, 0, stream>>>(bsum2, bexcl2, nb_scanT);
    k_scan_add   <<<(NT + BT) / BT, BT, 0, stream>>>(baseA, bexcl2, NT, E);
    k_binscatter <<<NBLK, BT, 0, stream>>>(row, col, baseA, ebuf, E, NBLK, NBK);
    k_bhist      <<<NBK, BT, 0, stream>>>(ebuf, baseA, deg, n, NBLK);
    k_scan_partial<<<nb_scanN, BT, 0, stream>>>(deg, off, bsum, n);
    k_scan_blocks<<<1, BT, 0, stream>>>(bsum, bexcl, nb_scanN);
    k_scan_add   <<<nb_n, BT, 0, stream>>>(off, bexcl, n, E);
    k_prep       <<<nb_n, BT, 0, stream>>>(deg, x, dinv, xs, n);
    k_bscatter   <<<NBK, BT, 0, stream>>>(ebuf, baseA, off, srow, n, NBLK);

    // GNN pipeline
    k_agg1       <<<nb_wave, BT, 0, stream>>>(xs, dinv, off, srow, aggx, n);
    k_mlp1       <<<nb_n, BT, 0, stream>>>(aggx, dinv, W1, b1, W2, hs, n);
    k_agg2       <<<nb_wave, BT, 0, stream>>>(hs, dinv, off, srow, agg2, n);
    k_pool       <<<nb_n, BT, 0, stream>>>(agg2, b2, batch, psum, pcnt, n);
    k_out        <<<1, 320, 0, stream>>>(psum, pcnt, Wl, bl, out);
}